// Round 13
// baseline (170.758 us; speedup 1.0000x reference)
//
#include <hip/hip_runtime.h>

#define HH 512
#define WW 512
#define HWSZ (HH * WW)
#define BLK 256

// ---- f32 weight LDS layout (float offsets) ----
// 16-wide rows padded to stride 20: fragment-gather addr (4*kg+e)*20+jj gives
// bank = jj + 16*kg (mod 32) -> 2-way aliasing = free (m136). Bias bases
// multiple of 4 floats (16B-aligned b128 reads).
#define SW1 20
#define O_W1 0       // 7 rows x 20
#define O_B1 140     // 16
#define O_W2 156     // 16 x 20
#define O_B2 476     // 16
#define O_W3 492     // 16 x 20
#define O_B3 812     // 16
#define O_W4 828     // 16 x 20
#define O_B4 1148    // 16
#define O_W5 1164    // 16 rows x stride 4 (3 used)
#define O_B5 1228    // 16 (rows 3-15 zero)
#define SWF_TOT 1244

// clang's AMDGPU builtins use __fp16 ('h') vectors (R9 lesson).
typedef __fp16 f16x2 __attribute__((ext_vector_type(2)));
typedef __fp16 f16x4 __attribute__((ext_vector_type(4)));
typedef float f32x4 __attribute__((ext_vector_type(4)));

// R10 lesson: no __has_builtin gating (host pass reports false for aux-target
// builtins); unconditional define compiles in both passes.
#define MFMA16(a, b, c) __builtin_amdgcn_mfma_f32_16x16x16f16((a), (b), (c), 0, 0, 0)

// RNE f32->f16 pair pack.
__device__ inline unsigned pk2u(float a, float b) {
    f16x2 p;
    p[0] = (__fp16)a;
    p[1] = (__fp16)b;
    return __builtin_bit_cast(unsigned, p);
}

// relu + f32x4 -> f16x4 (next layer's B fragment; element e = k-slot e)
__device__ inline f16x4 relu_pack(f32x4 d) {
    f16x4 r;
    r[0] = (__fp16)fmaxf(d[0], 0.f);
    r[1] = (__fp16)fmaxf(d[1], 0.f);
    r[2] = (__fp16)fmaxf(d[2], 0.f);
    r[3] = (__fp16)fmaxf(d[3], 0.f);
    return r;
}

// ---------------------------------------------------------------------------
// Pre-pass: (C,H,W) f32 -> paired-pixel f16 table, 16B/entry (4 MB).
// Entry (iy,ix) = {pixel(iy,ix), pixel(iy,min(ix+1,511))} as 2x f16x4.
// R12 diagnosis: gather cost is REQUEST RATE, not bytes — each corner load is
// a 64-lane random-address instr = 64 uncoalesced line requests. Pairing the
// two x-adjacent corners into one aligned 16B entry halves the request count
// (4 -> 2 loads/point) and bakes the x border clamp into the table
// (duplication at ix=511), with bit-identical f16 pixel values vs R12.
// ---------------------------------------------------------------------------
__global__ void fm_transpose_p(const float* __restrict__ fm, uint4* __restrict__ fmP) {
    int i = blockIdx.x * blockDim.x + threadIdx.x;
    if (i < HWSZ) {
        int ix = i & (WW - 1);
        int j = (ix < WW - 1) ? (i + 1) : i;  // x-neighbor, border-clamped
        f16x4 a, b;
        a[0] = (__fp16)fm[i];
        a[1] = (__fp16)fm[HWSZ + i];
        a[2] = (__fp16)fm[2 * HWSZ + i];
        a[3] = (__fp16)fm[3 * HWSZ + i];
        b[0] = (__fp16)fm[j];
        b[1] = (__fp16)fm[HWSZ + j];
        b[2] = (__fp16)fm[2 * HWSZ + j];
        b[3] = (__fp16)fm[3 * HWSZ + j];
        uint2 lo = __builtin_bit_cast(uint2, a);
        uint2 hi = __builtin_bit_cast(uint2, b);
        uint4 rec;
        rec.x = lo.x; rec.y = lo.y; rec.z = hi.x; rec.w = hi.y;
        fmP[i] = rec;
    }
}

// ---------------------------------------------------------------------------
// Fused grid_sample + MLP via per-wave MFMA (H = W^T * X, 16 points/column).
// Verified passing R11/R12 (absmax unchanged, MfmaUtil ~11%, VGPR 36).
// A row=l%16, k=4*(l/16)+e; B col=l%16, k same; D col=l%16, row=4*(l/16)+e.
// D layout == B layout -> layers chain in-register with relu+f16-pack only.
// ---------------------------------------------------------------------------
template <bool TR>
__global__ __launch_bounds__(BLK) void mlp_fused(
    const float* __restrict__ x, const void* __restrict__ fmv,
    const float* __restrict__ W1, const float* __restrict__ b1,
    const float* __restrict__ W2, const float* __restrict__ b2,
    const float* __restrict__ W3, const float* __restrict__ b3,
    const float* __restrict__ W4, const float* __restrict__ b4,
    const float* __restrict__ W5, const float* __restrict__ b5,
    float* __restrict__ out, int n)
{
    __shared__ __align__(16) float sW[SWF_TOT];
    __shared__ __align__(16) unsigned sX[BLK * 4];  // 4 packed dwords/point (f16 dims 0-7)
    const int tid = threadIdx.x;

    // ---- stage raw f32 weights into LDS (padded strides) ----
    if (tid < 112) { int r = tid >> 4, c = tid & 15; sW[O_W1 + r * SW1 + c] = W1[tid]; }
    if (tid < 16) {
        sW[O_B1 + tid] = b1[tid];
        sW[O_B2 + tid] = b2[tid];
        sW[O_B3 + tid] = b3[tid];
        sW[O_B4 + tid] = b4[tid];
        sW[O_B5 + tid] = (tid < 3) ? b5[tid] : 0.f;  // rows 3-15 zero (padded M)
    }
    {   // W2/W3/W4: one element per thread
        int r = tid >> 4, c = tid & 15;
        sW[O_W2 + r * SW1 + c] = W2[tid];
        sW[O_W3 + r * SW1 + c] = W3[tid];
        sW[O_W4 + r * SW1 + c] = W4[tid];
    }
    if (tid < 48) { int r = tid / 3, c = tid % 3; sW[O_W5 + r * 4 + c] = W5[tid]; }

    // ---- sampling: 1 point/thread (f32 coeffs, identical arithmetic) ----
    const int i = blockIdx.x * BLK + tid;
    const int ii = (i < n) ? i : (n - 1);  // clamp; store is predicated

    float p0 = x[3 * ii], p1 = x[3 * ii + 1], p2 = x[3 * ii + 2];

    float gx = p0 * 2.f - 1.f;
    float gy = p1 * 2.f - 1.f;
    float fx = ((gx + 1.f) * (float)WW - 1.f) * 0.5f;
    float fy = ((gy + 1.f) * (float)HH - 1.f) * 0.5f;
    fx = fminf(fmaxf(fx, 0.f), (float)(WW - 1));
    fy = fminf(fmaxf(fy, 0.f), (float)(HH - 1));
    float x0f = floorf(fx), y0f = floorf(fy);
    float wx = fx - x0f, wy = fy - y0f;
    int ix0 = (int)x0f, iy0 = (int)y0f;
    int ix1 = min(ix0 + 1, WW - 1);
    int iy1 = min(iy0 + 1, HH - 1);
    float w00 = (1.f - wy) * (1.f - wx);
    float w01 = (1.f - wy) * wx;
    float w10 = wy * (1.f - wx);
    float w11 = wy * wx;

    float feat[4];
    if (TR) {
        // paired table: one aligned 16B load per y-row gives both x-corners
        const uint4* fmP = reinterpret_cast<const uint4*>(fmv);
        uint4 r0 = fmP[iy0 * WW + ix0];
        uint4 r1 = fmP[iy1 * WW + ix0];
        f16x4 v00 = __builtin_bit_cast(f16x4, make_uint2(r0.x, r0.y));
        f16x4 v01 = __builtin_bit_cast(f16x4, make_uint2(r0.z, r0.w));
        f16x4 v10 = __builtin_bit_cast(f16x4, make_uint2(r1.x, r1.y));
        f16x4 v11 = __builtin_bit_cast(f16x4, make_uint2(r1.z, r1.w));
#pragma unroll
        for (int ch = 0; ch < 4; ++ch) {
            feat[ch] = (float)v00[ch] * w00 + (float)v01[ch] * w01 +
                       (float)v10[ch] * w10 + (float)v11[ch] * w11;
        }
    } else {
        const float* fmf = reinterpret_cast<const float*>(fmv);
#pragma unroll
        for (int ch = 0; ch < 4; ++ch) {
            const float* f = fmf + ch * HWSZ;
            feat[ch] = f[iy0 * WW + ix0] * w00 + f[iy0 * WW + ix1] * w01 +
                       f[iy1 * WW + ix0] * w10 + f[iy1 * WW + ix1] * w11;
        }
    }

    // ---- pack this point's 7 inputs (+pad) as 4 f16-pair dwords; stage ----
    {
        uint4 rec;
        rec.x = pk2u(p0, p1);
        rec.y = pk2u(p2, feat[0]);
        rec.z = pk2u(feat[1], feat[2]);
        rec.w = pk2u(feat[3], 0.f);
        reinterpret_cast<uint4*>(sX)[tid] = rec;  // 16B/lane contiguous
    }
    __syncthreads();

    // ---- per-lane fragment coordinates ----
    const int lane = tid & 63;
    const int wv = tid >> 6;       // wave within block (4 waves, 64 pts each)
    const int jj = lane & 15;      // A: output row m / B,D: point column
    const int kg = lane >> 4;      // k-slot group: k = 4*kg + e

    // ---- gather persistent weight A-fragments + bias C-fragments ----
    f16x4 A1, A2, A3, A4, A5;
#pragma unroll
    for (int e = 0; e < 4; ++e) {
        int k = 4 * kg + e;
        A1[e] = (__fp16)((k < 7) ? sW[O_W1 + k * SW1 + jj] : 0.f);
        A2[e] = (__fp16)sW[O_W2 + k * SW1 + jj];
        A3[e] = (__fp16)sW[O_W3 + k * SW1 + jj];
        A4[e] = (__fp16)sW[O_W4 + k * SW1 + jj];
        A5[e] = (__fp16)((jj < 3) ? sW[O_W5 + k * 4 + jj] : 0.f);
    }
    f32x4 C1 = *reinterpret_cast<const f32x4*>(sW + O_B1 + 4 * kg);
    f32x4 C2 = *reinterpret_cast<const f32x4*>(sW + O_B2 + 4 * kg);
    f32x4 C3 = *reinterpret_cast<const f32x4*>(sW + O_B3 + 4 * kg);
    f32x4 C4 = *reinterpret_cast<const f32x4*>(sW + O_B4 + 4 * kg);
    f32x4 C5 = *reinterpret_cast<const f32x4*>(sW + O_B5 + 4 * kg);

    // ---- load B fragments for the wave's 4 point-groups (L1: k=0..15,
    //      dims 8-15 zero => only kg<2 lanes read) ----
    f16x4 B0, B1f, B2f, B3f;
    {
        const int pb = wv * 64;  // block-local point base for this wave
#define LOADB(Bv, g)                                                         \
        {                                                                    \
            uint2 raw = make_uint2(0u, 0u);                                  \
            if (kg < 2)                                                      \
                raw = *reinterpret_cast<const uint2*>(                       \
                    sX + (pb + (g) * 16 + jj) * 4 + kg * 2);                 \
            (Bv) = __builtin_bit_cast(f16x4, raw);                           \
        }
        LOADB(B0, 0) LOADB(B1f, 1) LOADB(B2f, 2) LOADB(B3f, 3)
#undef LOADB
    }

    // ---- 5-layer MLP: 4 independent MFMA chains (one per 16-point group) ----
    f32x4 D0, D1, D2, D3;
    // layer 1 (K padded 7->16; A zero for k>=7)
    D0 = MFMA16(A1, B0, C1);  D1 = MFMA16(A1, B1f, C1);
    D2 = MFMA16(A1, B2f, C1); D3 = MFMA16(A1, B3f, C1);
    B0 = relu_pack(D0); B1f = relu_pack(D1); B2f = relu_pack(D2); B3f = relu_pack(D3);
    // layer 2
    D0 = MFMA16(A2, B0, C2);  D1 = MFMA16(A2, B1f, C2);
    D2 = MFMA16(A2, B2f, C2); D3 = MFMA16(A2, B3f, C2);
    B0 = relu_pack(D0); B1f = relu_pack(D1); B2f = relu_pack(D2); B3f = relu_pack(D3);
    // layer 3
    D0 = MFMA16(A3, B0, C3);  D1 = MFMA16(A3, B1f, C3);
    D2 = MFMA16(A3, B2f, C3); D3 = MFMA16(A3, B3f, C3);
    B0 = relu_pack(D0); B1f = relu_pack(D1); B2f = relu_pack(D2); B3f = relu_pack(D3);
    // layer 4
    D0 = MFMA16(A4, B0, C4);  D1 = MFMA16(A4, B1f, C4);
    D2 = MFMA16(A4, B2f, C4); D3 = MFMA16(A4, B3f, C4);
    B0 = relu_pack(D0); B1f = relu_pack(D1); B2f = relu_pack(D2); B3f = relu_pack(D3);
    // layer 5 (M padded 3->16, no relu)
    D0 = MFMA16(A5, B0, C5);  D1 = MFMA16(A5, B1f, C5);
    D2 = MFMA16(A5, B2f, C5); D3 = MFMA16(A5, B3f, C5);

    // ---- store: D col=point (jj), row=output dim (4*kg+e) => lanes kg==0
    //      hold dims 0-2 of their group's point in regs 0-2 ----
    if (kg == 0) {
        const int gbase = blockIdx.x * BLK + wv * 64 + jj;
#define STOREG(Dv, g)                                                        \
        {                                                                    \
            int gp = gbase + (g) * 16;                                       \
            if (gp < n) {                                                    \
                out[3 * gp]     = (Dv)[0];                                   \
                out[3 * gp + 1] = (Dv)[1];                                   \
                out[3 * gp + 2] = (Dv)[2];                                   \
            }                                                                \
        }
        STOREG(D0, 0) STOREG(D1, 1) STOREG(D2, 2) STOREG(D3, 3)
#undef STOREG
    }
}

extern "C" void kernel_launch(void* const* d_in, const int* in_sizes, int n_in,
                              void* d_out, int out_size, void* d_ws, size_t ws_size,
                              hipStream_t stream) {
    const float* x  = (const float*)d_in[0];
    const float* fm = (const float*)d_in[1];
    const float* W1 = (const float*)d_in[2];
    const float* b1 = (const float*)d_in[3];
    const float* W2 = (const float*)d_in[4];
    const float* b2 = (const float*)d_in[5];
    const float* W3 = (const float*)d_in[6];
    const float* b3 = (const float*)d_in[7];
    const float* W4 = (const float*)d_in[8];
    const float* b4 = (const float*)d_in[9];
    const float* W5 = (const float*)d_in[10];
    const float* b5 = (const float*)d_in[11];
    float* out = (float*)d_out;

    const int n = in_sizes[0] / 3;  // 4,000,000 points
    const int grid = (n + BLK - 1) / BLK;

    const size_t need = (size_t)HWSZ * sizeof(uint4);  // 4 MB paired table
    if (ws_size >= need) {
        uint4* fmP = (uint4*)d_ws;
        fm_transpose_p<<<(HWSZ + 255) / 256, 256, 0, stream>>>(fm, fmP);
        mlp_fused<true><<<grid, BLK, 0, stream>>>(x, (const void*)fmP, W1, b1,
                                                  W2, b2, W3, b3, W4, b4, W5, b5,
                                                  out, n);
    } else {
        mlp_fused<false><<<grid, BLK, 0, stream>>>(x, (const void*)fm, W1, b1,
                                                   W2, b2, W3, b3, W4, b4, W5, b5,
                                                   out, n);
    }
}

// Round 14
// 166.465 us; speedup vs baseline: 1.0258x; 1.0258x over previous
//
#include <hip/hip_runtime.h>

#define HH 512
#define WW 512
#define HWSZ (HH * WW)
#define BLK 256
#define TPB 8   // tiles (of BLK points) per block; pipelined double-buffer

// ---- f32 weight LDS layout (float offsets) ----
#define SW1 20
#define O_W1 0       // 7 rows x 20
#define O_B1 140     // 16
#define O_W2 156     // 16 x 20
#define O_B2 476     // 16
#define O_W3 492     // 16 x 20
#define O_B3 812     // 16
#define O_W4 828     // 16 x 20
#define O_B4 1148    // 16
#define O_W5 1164    // 16 rows x stride 4 (3 used)
#define O_B5 1228    // 16 (rows 3-15 zero)
#define SWF_TOT 1244

// clang's AMDGPU builtins use __fp16 ('h') vectors (R9 lesson).
typedef __fp16 f16x2 __attribute__((ext_vector_type(2)));
typedef __fp16 f16x4 __attribute__((ext_vector_type(4)));
typedef float f32x4 __attribute__((ext_vector_type(4)));

// R10 lesson: no __has_builtin gating (host pass reports false for
// aux-target builtins); unconditional define compiles in both passes.
#define MFMA16(a, b, c) __builtin_amdgcn_mfma_f32_16x16x16f16((a), (b), (c), 0, 0, 0)

// RNE f32->f16 pair pack.
__device__ inline unsigned pk2u(float a, float b) {
    f16x2 p;
    p[0] = (__fp16)a;
    p[1] = (__fp16)b;
    return __builtin_bit_cast(unsigned, p);
}

// relu + f32x4 -> f16x4 (next layer's B fragment)
__device__ inline f16x4 relu_pack(f32x4 d) {
    f16x4 r;
    r[0] = (__fp16)fmaxf(d[0], 0.f);
    r[1] = (__fp16)fmaxf(d[1], 0.f);
    r[2] = (__fp16)fmaxf(d[2], 0.f);
    r[3] = (__fp16)fmaxf(d[3], 0.f);
    return r;
}

// ---------------------------------------------------------------------------
// Pre-pass: (C,H,W) f32 -> (H,W,C) f16x4, 8B/pixel, 2 MB (R12's table — the
// best measured: L2-resident, FETCH 32MB. R13's 4MB paired table thrashed L2,
// FETCH 114MB, dur flat -> request count is NOT the binding term; reverted).
// ---------------------------------------------------------------------------
__global__ void fm_transpose_h(const float* __restrict__ fm, f16x4* __restrict__ fmT) {
    int i = blockIdx.x * blockDim.x + threadIdx.x;
    if (i < HWSZ) {
        f16x4 v;
        v[0] = (__fp16)fm[i];
        v[1] = (__fp16)fm[HWSZ + i];
        v[2] = (__fp16)fm[2 * HWSZ + i];
        v[3] = (__fp16)fm[3 * HWSZ + i];
        fmT[i] = v;
    }
}

// ---------------------------------------------------------------------------
// Fused grid_sample + MLP via per-wave MFMA — PIPELINED over TPB tiles/block.
// R13 residual model: ~45us of the 76us is exposed gather latency (x-load ->
// addr -> 4 dependent gathers -> pack -> barrier strictly BEFORE the MFMA
// section; barrier waits on the slowest of 256 lanes). This version double-
// buffers sX and runs a 2-deep pipeline: x-loads issued 2 tiles ahead,
// gathers 1 tile ahead, so the load chains fly under tile t's 20 MFMAs.
// MFMA structure verified in R11/R12 (absmax unchanged, VGPR 36).
// ---------------------------------------------------------------------------
template <bool TR>
__global__ __launch_bounds__(BLK) void mlp_fused(
    const float* __restrict__ x, const void* __restrict__ fmv,
    const float* __restrict__ W1, const float* __restrict__ b1,
    const float* __restrict__ W2, const float* __restrict__ b2,
    const float* __restrict__ W3, const float* __restrict__ b3,
    const float* __restrict__ W4, const float* __restrict__ b4,
    const float* __restrict__ W5, const float* __restrict__ b5,
    float* __restrict__ out, int n)
{
    __shared__ __align__(16) float sW[SWF_TOT];
    __shared__ __align__(16) unsigned sX[2][BLK * 4];
    const int tid = threadIdx.x;

    // ---- stage raw f32 weights into LDS (padded strides) ----
    if (tid < 112) { int r = tid >> 4, c = tid & 15; sW[O_W1 + r * SW1 + c] = W1[tid]; }
    if (tid < 16) {
        sW[O_B1 + tid] = b1[tid];
        sW[O_B2 + tid] = b2[tid];
        sW[O_B3 + tid] = b3[tid];
        sW[O_B4 + tid] = b4[tid];
        sW[O_B5 + tid] = (tid < 3) ? b5[tid] : 0.f;
    }
    {
        int r = tid >> 4, c = tid & 15;
        sW[O_W2 + r * SW1 + c] = W2[tid];
        sW[O_W3 + r * SW1 + c] = W3[tid];
        sW[O_W4 + r * SW1 + c] = W4[tid];
    }
    if (tid < 48) { int r = tid / 3, c = tid % 3; sW[O_W5 + r * 4 + c] = W5[tid]; }

    const int lane = tid & 63;
    const int wv = tid >> 6;
    const int jj = lane & 15;
    const int kg = lane >> 4;
    const int tile0 = blockIdx.x * TPB;

    const f16x4* fmH = reinterpret_cast<const f16x4*>(fmv);
    const float* fmf = reinterpret_cast<const float*>(fmv);

    // ---- pipeline state ----
    float pa0, pa1, pa2;            // coords of tile about to be interped
    float pb0, pb1, pb2;            // coords in flight (2 ahead)
    uint2 gv00, gv01, gv10, gv11;   // TR gathers in flight (1 ahead)

    auto loadX = [&](int t, float& q0, float& q1, float& q2) {
        int p = (tile0 + t) * BLK + tid;
        int ii = (p < n) ? p : (n - 1);     // clamp; stores predicated
        q0 = x[3 * ii]; q1 = x[3 * ii + 1]; q2 = x[3 * ii + 2];
    };
    auto addr = [&](float q0, float q1, int& ix0, int& iy0, int& ix1, int& iy1,
                    float& wxo, float& wyo) {
        float gx = q0 * 2.f - 1.f;
        float gy = q1 * 2.f - 1.f;
        float fx = ((gx + 1.f) * (float)WW - 1.f) * 0.5f;
        float fy = ((gy + 1.f) * (float)HH - 1.f) * 0.5f;
        fx = fminf(fmaxf(fx, 0.f), (float)(WW - 1));
        fy = fminf(fmaxf(fy, 0.f), (float)(HH - 1));
        float x0f = floorf(fx), y0f = floorf(fy);
        wxo = fx - x0f; wyo = fy - y0f;
        ix0 = (int)x0f; iy0 = (int)y0f;
        ix1 = min(ix0 + 1, WW - 1);
        iy1 = min(iy0 + 1, HH - 1);
    };
    auto issueG = [&](float q0, float q1) {   // TR only: fire the 4 gathers
        if (TR) {
            int ix0, iy0, ix1, iy1; float wxo, wyo;
            addr(q0, q1, ix0, iy0, ix1, iy1, wxo, wyo);
            const uint2* f2 = reinterpret_cast<const uint2*>(fmH);
            gv00 = f2[iy0 * WW + ix0];
            gv01 = f2[iy0 * WW + ix1];
            gv10 = f2[iy1 * WW + ix0];
            gv11 = f2[iy1 * WW + ix1];
        }
    };
    auto interpPackWrite = [&](float q0, float q1, float q2, int buf) {
        int ix0, iy0, ix1, iy1; float wxo, wyo;
        addr(q0, q1, ix0, iy0, ix1, iy1, wxo, wyo);  // recompute (cheap) — keeps live state small
        float w00 = (1.f - wyo) * (1.f - wxo);
        float w01 = (1.f - wyo) * wxo;
        float w10 = wyo * (1.f - wxo);
        float w11 = wyo * wxo;
        float feat[4];
        if (TR) {
            f16x4 v00 = __builtin_bit_cast(f16x4, gv00);
            f16x4 v01 = __builtin_bit_cast(f16x4, gv01);
            f16x4 v10 = __builtin_bit_cast(f16x4, gv10);
            f16x4 v11 = __builtin_bit_cast(f16x4, gv11);
#pragma unroll
            for (int ch = 0; ch < 4; ++ch) {
                feat[ch] = (float)v00[ch] * w00 + (float)v01[ch] * w01 +
                           (float)v10[ch] * w10 + (float)v11[ch] * w11;
            }
        } else {
#pragma unroll
            for (int ch = 0; ch < 4; ++ch) {
                const float* f = fmf + ch * HWSZ;
                feat[ch] = f[iy0 * WW + ix0] * w00 + f[iy0 * WW + ix1] * w01 +
                           f[iy1 * WW + ix0] * w10 + f[iy1 * WW + ix1] * w11;
            }
        }
        uint4 rec;
        rec.x = pk2u(q0, q1);
        rec.y = pk2u(q2, feat[0]);
        rec.z = pk2u(feat[1], feat[2]);
        rec.w = pk2u(feat[3], 0.f);
        reinterpret_cast<uint4*>(sX[buf])[tid] = rec;
    };

    // ---- persistent weight A-fragments + bias C-fragments (filled post-barrier) ----
    f16x4 A1, A2, A3, A4, A5;
    f32x4 C1, C2, C3, C4, C5;

    auto runTile = [&](int t, int buf) {
        const unsigned* sxb = sX[buf];
        f16x4 B0, B1f, B2f, B3f;
        const int pb = wv * 64;
#define LOADB(Bv, g)                                                         \
        {                                                                    \
            uint2 raw = make_uint2(0u, 0u);                                  \
            if (kg < 2)                                                      \
                raw = *reinterpret_cast<const uint2*>(                       \
                    sxb + (pb + (g) * 16 + jj) * 4 + kg * 2);                \
            (Bv) = __builtin_bit_cast(f16x4, raw);                           \
        }
        LOADB(B0, 0) LOADB(B1f, 1) LOADB(B2f, 2) LOADB(B3f, 3)
#undef LOADB
        f32x4 D0, D1, D2, D3;
        D0 = MFMA16(A1, B0, C1);  D1 = MFMA16(A1, B1f, C1);
        D2 = MFMA16(A1, B2f, C1); D3 = MFMA16(A1, B3f, C1);
        B0 = relu_pack(D0); B1f = relu_pack(D1); B2f = relu_pack(D2); B3f = relu_pack(D3);
        D0 = MFMA16(A2, B0, C2);  D1 = MFMA16(A2, B1f, C2);
        D2 = MFMA16(A2, B2f, C2); D3 = MFMA16(A2, B3f, C2);
        B0 = relu_pack(D0); B1f = relu_pack(D1); B2f = relu_pack(D2); B3f = relu_pack(D3);
        D0 = MFMA16(A3, B0, C3);  D1 = MFMA16(A3, B1f, C3);
        D2 = MFMA16(A3, B2f, C3); D3 = MFMA16(A3, B3f, C3);
        B0 = relu_pack(D0); B1f = relu_pack(D1); B2f = relu_pack(D2); B3f = relu_pack(D3);
        D0 = MFMA16(A4, B0, C4);  D1 = MFMA16(A4, B1f, C4);
        D2 = MFMA16(A4, B2f, C4); D3 = MFMA16(A4, B3f, C4);
        B0 = relu_pack(D0); B1f = relu_pack(D1); B2f = relu_pack(D2); B3f = relu_pack(D3);
        D0 = MFMA16(A5, B0, C5);  D1 = MFMA16(A5, B1f, C5);
        D2 = MFMA16(A5, B2f, C5); D3 = MFMA16(A5, B3f, C5);
        if (kg == 0) {
            const int gbase = (tile0 + t) * BLK + wv * 64 + jj;
#define STOREG(Dv, g)                                                        \
            {                                                                \
                int gp = gbase + (g) * 16;                                   \
                if (gp < n) {                                                \
                    out[3 * gp]     = (Dv)[0];                               \
                    out[3 * gp + 1] = (Dv)[1];                               \
                    out[3 * gp + 2] = (Dv)[2];                               \
                }                                                            \
            }
            STOREG(D0, 0) STOREG(D1, 1) STOREG(D2, 2) STOREG(D3, 3)
#undef STOREG
        }
    };

    // ---- prologue: tile 0 sampled pre-barrier; tile 1 primed ----
    {
        float q0, q1, q2;
        loadX(0, q0, q1, q2);
        issueG(q0, q1);
        interpPackWrite(q0, q1, q2, 0);
    }
    loadX(1, pa0, pa1, pa2);
    __syncthreads();   // sW + sX[0] visible to all

    // fragment gather (once per thread)
#pragma unroll
    for (int e = 0; e < 4; ++e) {
        int k = 4 * kg + e;
        A1[e] = (__fp16)((k < 7) ? sW[O_W1 + k * SW1 + jj] : 0.f);
        A2[e] = (__fp16)sW[O_W2 + k * SW1 + jj];
        A3[e] = (__fp16)sW[O_W3 + k * SW1 + jj];
        A4[e] = (__fp16)sW[O_W4 + k * SW1 + jj];
        A5[e] = (__fp16)((jj < 3) ? sW[O_W5 + k * 4 + jj] : 0.f);
    }
    C1 = *reinterpret_cast<const f32x4*>(sW + O_B1 + 4 * kg);
    C2 = *reinterpret_cast<const f32x4*>(sW + O_B2 + 4 * kg);
    C3 = *reinterpret_cast<const f32x4*>(sW + O_B3 + 4 * kg);
    C4 = *reinterpret_cast<const f32x4*>(sW + O_B4 + 4 * kg);
    C5 = *reinterpret_cast<const f32x4*>(sW + O_B5 + 4 * kg);

    issueG(pa0, pa1);  // gathers for tile 1 in flight

    // ---- pipelined main loop.  Invariant entering iter t:
    //      sX[t&1] holds tile t (barrier passed); pa = coords(t+1);
    //      gv = gathers(t+1). ----
#pragma unroll 1
    for (int t = 0; t < TPB; ++t) {
        const int cur = t & 1;
        if (t + 2 < TPB) loadX(t + 2, pb0, pb1, pb2);   // x 2 ahead
        runTile(t, cur);                                // MFMA on tile t
        if (t + 1 < TPB) interpPackWrite(pa0, pa1, pa2, cur ^ 1);  // finish t+1
        pa0 = pb0; pa1 = pb1; pa2 = pb2;
        __syncthreads();                                // writes of cur^1 visible
        if (t + 2 < TPB) issueG(pa0, pa1);              // gathers 1 ahead
    }
}

extern "C" void kernel_launch(void* const* d_in, const int* in_sizes, int n_in,
                              void* d_out, int out_size, void* d_ws, size_t ws_size,
                              hipStream_t stream) {
    const float* x  = (const float*)d_in[0];
    const float* fm = (const float*)d_in[1];
    const float* W1 = (const float*)d_in[2];
    const float* b1 = (const float*)d_in[3];
    const float* W2 = (const float*)d_in[4];
    const float* b2 = (const float*)d_in[5];
    const float* W3 = (const float*)d_in[6];
    const float* b3 = (const float*)d_in[7];
    const float* W4 = (const float*)d_in[8];
    const float* b4 = (const float*)d_in[9];
    const float* W5 = (const float*)d_in[10];
    const float* b5 = (const float*)d_in[11];
    float* out = (float*)d_out;

    const int n = in_sizes[0] / 3;  // 4,000,000 points
    const int tiles = (n + BLK - 1) / BLK;
    const int grid = (tiles + TPB - 1) / TPB;

    const size_t need = (size_t)HWSZ * sizeof(f16x4);  // 2 MB f16 table
    if (ws_size >= need) {
        f16x4* fmT = (f16x4*)d_ws;
        fm_transpose_h<<<(HWSZ + 255) / 256, 256, 0, stream>>>(fm, fmT);
        mlp_fused<true><<<grid, BLK, 0, stream>>>(x, (const void*)fmT, W1, b1,
                                                  W2, b2, W3, b3, W4, b4, W5, b5,
                                                  out, n);
    } else {
        mlp_fused<false><<<grid, BLK, 0, stream>>>(x, (const void*)fm, W1, b1,
                                                   W2, b2, W3, b3, W4, b4, W5, b5,
                                                   out, n);
    }
}

// Round 15
// 164.079 us; speedup vs baseline: 1.0407x; 1.0145x over previous
//
#include <hip/hip_runtime.h>

#define HH 512
#define WW 512
#define HWSZ (HH * WW)
#define BLK 256
#define TPB 4   // tiles/block. R14's TPB=8 -> only 1953 blocks, occupancy 38%;
                // 3907 blocks rebalances CUs while keeping the pipeline.

// ---- f32 weight LDS layout (float offsets) ----
// W1 staged as 8 rows (x0,x1,x2,ZERO,f0,f1,f2,f3) matching the new input
// record [p0,p1,p2,0,f0..f3] (lets packed-f16 interp write feat directly).
#define SW1 20
#define O_W1 0       // 8 rows x 20
#define O_W2 160     // 16 x 20
#define O_W3 480
#define O_W4 800
#define O_W5 1120    // 16 rows x stride 4 (3 used)
#define O_B1 1184
#define O_B2 1200
#define O_B3 1216
#define O_B4 1232
#define O_B5 1248    // 16 (rows 3-15 zero)
#define SWF_TOT 1264

// __fp16 vectors at builtin boundaries (R9); _Float16 vectors for ARITHMETIC
// (__fp16 is storage-only in C++ — scalar/vector arith wants _Float16).
typedef __fp16 f16x2 __attribute__((ext_vector_type(2)));
typedef __fp16 f16x4 __attribute__((ext_vector_type(4)));
typedef _Float16 h16x4 __attribute__((ext_vector_type(4)));
typedef float f32x4 __attribute__((ext_vector_type(4)));

// R10 lesson: no __has_builtin gating (false in host pass for aux-target
// builtins, though the builtins themselves are callable — MFMA16 proved it).
#define MFMA16(a, b, c) __builtin_amdgcn_mfma_f32_16x16x16f16((a), (b), (c), 0, 0, 0)

// RNE f32->f16 pair pack (coords).
__device__ inline unsigned pk2u(float a, float b) {
    f16x2 p;
    p[0] = (__fp16)a;
    p[1] = (__fp16)b;
    return __builtin_bit_cast(unsigned, p);
}

// relu + pack, 4 VALU (was 8): v_cvt_pkrtz x2 + v_pk_max_f16 x2.
// relu(rtz(x)) == rtz(relu(x)) (rtz is monotone, sign-preserving).
__device__ inline f16x4 relu_pack(f32x4 d) {
    f16x2 lo = __builtin_amdgcn_cvt_pkrtz(d[0], d[1]);
    f16x2 hi = __builtin_amdgcn_cvt_pkrtz(d[2], d[3]);
    uint2 u = make_uint2(__builtin_bit_cast(unsigned, lo),
                         __builtin_bit_cast(unsigned, hi));
    h16x4 r = __builtin_bit_cast(h16x4, u);
    h16x4 z = {};
    r = __builtin_elementwise_max(r, z);
    return __builtin_bit_cast(f16x4, r);
}

// ---------------------------------------------------------------------------
// Pre-pass: (C,H,W) f32 -> (H,W,C) f16x4, 8B/pixel, 2 MB (R12 table: best
// measured — L2-resident, FETCH 32MB; R13's 4MB pairing thrashed L2).
// ---------------------------------------------------------------------------
__global__ void fm_transpose_h(const float* __restrict__ fm, f16x4* __restrict__ fmT) {
    int i = blockIdx.x * blockDim.x + threadIdx.x;
    if (i < HWSZ) {
        f16x4 v;
        v[0] = (__fp16)fm[i];
        v[1] = (__fp16)fm[HWSZ + i];
        v[2] = (__fp16)fm[2 * HWSZ + i];
        v[3] = (__fp16)fm[3 * HWSZ + i];
        fmT[i] = v;
    }
}

// ---------------------------------------------------------------------------
// Fused grid_sample + MLP via per-wave MFMA, pipelined (R14 structure) with a
// packed-f16 VALU diet. R14 tally at 71us: MFMA ~8us, gather-side levers
// exhausted (R13/R14 nulls), VALUBusy 52% == ~37us if real-cycled — dominated
// by relu_pack (128/240 instr per thread-tile) and f32 interp+pack. This
// version: relu_pack 8->4 ops, interp via v_pk_fma_f16 writing feat f16x4
// straight into the record, addr computed once (wx,wy stashed).
// ---------------------------------------------------------------------------
template <bool TR>
__global__ __launch_bounds__(BLK) void mlp_fused(
    const float* __restrict__ x, const void* __restrict__ fmv,
    const float* __restrict__ W1, const float* __restrict__ b1,
    const float* __restrict__ W2, const float* __restrict__ b2,
    const float* __restrict__ W3, const float* __restrict__ b3,
    const float* __restrict__ W4, const float* __restrict__ b4,
    const float* __restrict__ W5, const float* __restrict__ b5,
    float* __restrict__ out, int n)
{
    __shared__ __align__(16) float sW[SWF_TOT];
    __shared__ __align__(16) unsigned sX[2][BLK * 4];
    const int tid = threadIdx.x;

    // ---- stage weights into LDS ----
    if (tid < 112) {  // W1 rows remapped: 0,1,2 -> 0,1,2 ; 3..6 -> 4..7
        int r = tid >> 4, c = tid & 15;
        int rr = (r < 3) ? r : r + 1;
        sW[O_W1 + rr * SW1 + c] = W1[tid];
    }
    if (tid >= 112 && tid < 132) sW[O_W1 + 3 * SW1 + (tid - 112)] = 0.f;  // zero row 3
    if (tid < 16) {
        sW[O_B1 + tid] = b1[tid];
        sW[O_B2 + tid] = b2[tid];
        sW[O_B3 + tid] = b3[tid];
        sW[O_B4 + tid] = b4[tid];
        sW[O_B5 + tid] = (tid < 3) ? b5[tid] : 0.f;
    }
    {
        int r = tid >> 4, c = tid & 15;
        sW[O_W2 + r * SW1 + c] = W2[tid];
        sW[O_W3 + r * SW1 + c] = W3[tid];
        sW[O_W4 + r * SW1 + c] = W4[tid];
    }
    if (tid < 48) { int r = tid / 3, c = tid % 3; sW[O_W5 + r * 4 + c] = W5[tid]; }

    const int lane = tid & 63;
    const int wv = tid >> 6;
    const int jj = lane & 15;
    const int kg = lane >> 4;
    const int tile0 = blockIdx.x * TPB;

    const float* fmf = reinterpret_cast<const float*>(fmv);

    // ---- pipeline state ----
    float pa0, pa1, pa2, pb0, pb1, pb2;
    uint2 gv00, gv01, gv10, gv11;   // gathers in flight (1 tile ahead)
    float wxs, wys;                 // stashed interp fractions (addr done ONCE)

    auto loadX = [&](int t, float& q0, float& q1, float& q2) {
        int p = (tile0 + t) * BLK + tid;
        int ii = (p < n) ? p : (n - 1);
        q0 = x[3 * ii]; q1 = x[3 * ii + 1]; q2 = x[3 * ii + 2];
    };
    auto addr = [&](float q0, float q1, int& ix0, int& iy0, int& ix1, int& iy1,
                    float& wxo, float& wyo) {
        float gx = q0 * 2.f - 1.f;
        float gy = q1 * 2.f - 1.f;
        float fx = ((gx + 1.f) * (float)WW - 1.f) * 0.5f;
        float fy = ((gy + 1.f) * (float)HH - 1.f) * 0.5f;
        fx = fminf(fmaxf(fx, 0.f), (float)(WW - 1));
        fy = fminf(fmaxf(fy, 0.f), (float)(HH - 1));
        float x0f = floorf(fx), y0f = floorf(fy);
        wxo = fx - x0f; wyo = fy - y0f;
        ix0 = (int)x0f; iy0 = (int)y0f;
        ix1 = min(ix0 + 1, WW - 1);
        iy1 = min(iy0 + 1, HH - 1);
    };
    auto issueG = [&](float q0, float q1) {
        if (TR) {
            int ix0, iy0, ix1, iy1;
            addr(q0, q1, ix0, iy0, ix1, iy1, wxs, wys);
            const uint2* f2 = reinterpret_cast<const uint2*>(fmv);
            gv00 = f2[iy0 * WW + ix0];
            gv01 = f2[iy0 * WW + ix1];
            gv10 = f2[iy1 * WW + ix0];
            gv11 = f2[iy1 * WW + ix1];
        }
    };
    auto interpPackWrite = [&](float q0, float q1, float q2, int buf) {
        uint2 fz;
        if (TR) {
            // packed-f16 bilinear: 2 pk_mul + 6 pk_fma + weight prep
            float w00 = (1.f - wys) * (1.f - wxs);
            float w01 = (1.f - wys) * wxs;
            float w10 = wys * (1.f - wxs);
            float w11 = wys * wxs;
            _Float16 h00 = (_Float16)w00, h01 = (_Float16)w01;
            _Float16 h10 = (_Float16)w10, h11 = (_Float16)w11;
            h16x4 W00 = {h00, h00, h00, h00}, W01 = {h01, h01, h01, h01};
            h16x4 W10 = {h10, h10, h10, h10}, W11 = {h11, h11, h11, h11};
            h16x4 v00 = __builtin_bit_cast(h16x4, gv00);
            h16x4 v01 = __builtin_bit_cast(h16x4, gv01);
            h16x4 v10 = __builtin_bit_cast(h16x4, gv10);
            h16x4 v11 = __builtin_bit_cast(h16x4, gv11);
            h16x4 acc = v00 * W00 + v01 * W01 + v10 * W10 + v11 * W11;
            fz = __builtin_bit_cast(uint2, acc);
        } else {
            int ix0, iy0, ix1, iy1; float wxo, wyo;
            addr(q0, q1, ix0, iy0, ix1, iy1, wxo, wyo);
            float w00 = (1.f - wyo) * (1.f - wxo);
            float w01 = (1.f - wyo) * wxo;
            float w10 = wyo * (1.f - wxo);
            float w11 = wyo * wxo;
            float feat[4];
#pragma unroll
            for (int ch = 0; ch < 4; ++ch) {
                const float* f = fmf + ch * HWSZ;
                feat[ch] = f[iy0 * WW + ix0] * w00 + f[iy0 * WW + ix1] * w01 +
                           f[iy1 * WW + ix0] * w10 + f[iy1 * WW + ix1] * w11;
            }
            fz.x = pk2u(feat[0], feat[1]);
            fz.y = pk2u(feat[2], feat[3]);
        }
        uint4 rec;
        rec.x = pk2u(q0, q1);
        rec.y = pk2u(q2, 0.f);   // slot 3 = pad (W1 row 3 zeroed)
        rec.z = fz.x;
        rec.w = fz.y;
        reinterpret_cast<uint4*>(sX[buf])[tid] = rec;
    };

    // ---- persistent weight A-fragments + bias C-fragments ----
    f16x4 A1, A2, A3, A4, A5;
    f32x4 C1, C2, C3, C4, C5;

    auto runTile = [&](int t, int buf) {
        const unsigned* sxb = sX[buf];
        f16x4 B0, B1f, B2f, B3f;
        const int pb = wv * 64;
#define LOADB(Bv, g)                                                         \
        {                                                                    \
            uint2 raw = make_uint2(0u, 0u);                                  \
            if (kg < 2)                                                      \
                raw = *reinterpret_cast<const uint2*>(                       \
                    sxb + (pb + (g) * 16 + jj) * 4 + kg * 2);                \
            (Bv) = __builtin_bit_cast(f16x4, raw);                           \
        }
        LOADB(B0, 0) LOADB(B1f, 1) LOADB(B2f, 2) LOADB(B3f, 3)
#undef LOADB
        f32x4 D0, D1, D2, D3;
        D0 = MFMA16(A1, B0, C1);  D1 = MFMA16(A1, B1f, C1);
        D2 = MFMA16(A1, B2f, C1); D3 = MFMA16(A1, B3f, C1);
        B0 = relu_pack(D0); B1f = relu_pack(D1); B2f = relu_pack(D2); B3f = relu_pack(D3);
        D0 = MFMA16(A2, B0, C2);  D1 = MFMA16(A2, B1f, C2);
        D2 = MFMA16(A2, B2f, C2); D3 = MFMA16(A2, B3f, C2);
        B0 = relu_pack(D0); B1f = relu_pack(D1); B2f = relu_pack(D2); B3f = relu_pack(D3);
        D0 = MFMA16(A3, B0, C3);  D1 = MFMA16(A3, B1f, C3);
        D2 = MFMA16(A3, B2f, C3); D3 = MFMA16(A3, B3f, C3);
        B0 = relu_pack(D0); B1f = relu_pack(D1); B2f = relu_pack(D2); B3f = relu_pack(D3);
        D0 = MFMA16(A4, B0, C4);  D1 = MFMA16(A4, B1f, C4);
        D2 = MFMA16(A4, B2f, C4); D3 = MFMA16(A4, B3f, C4);
        B0 = relu_pack(D0); B1f = relu_pack(D1); B2f = relu_pack(D2); B3f = relu_pack(D3);
        D0 = MFMA16(A5, B0, C5);  D1 = MFMA16(A5, B1f, C5);
        D2 = MFMA16(A5, B2f, C5); D3 = MFMA16(A5, B3f, C5);
        if (kg == 0) {
            const int gbase = (tile0 + t) * BLK + wv * 64 + jj;
#define STOREG(Dv, g)                                                        \
            {                                                                \
                int gp = gbase + (g) * 16;                                   \
                if (gp < n) {                                                \
                    out[3 * gp]     = (Dv)[0];                               \
                    out[3 * gp + 1] = (Dv)[1];                               \
                    out[3 * gp + 2] = (Dv)[2];                               \
                }                                                            \
            }
            STOREG(D0, 0) STOREG(D1, 1) STOREG(D2, 2) STOREG(D3, 3)
#undef STOREG
        }
    };

    // ---- prologue: tile 0 sampled pre-barrier; tile 1 primed ----
    {
        float q0, q1, q2;
        loadX(0, q0, q1, q2);
        issueG(q0, q1);
        interpPackWrite(q0, q1, q2, 0);
    }
    loadX(1, pa0, pa1, pa2);
    __syncthreads();

    // fragment gather (once per thread); W1 staged as 8 rows (k<8)
#pragma unroll
    for (int e = 0; e < 4; ++e) {
        int k = 4 * kg + e;
        A1[e] = (__fp16)((k < 8) ? sW[O_W1 + k * SW1 + jj] : 0.f);
        A2[e] = (__fp16)sW[O_W2 + k * SW1 + jj];
        A3[e] = (__fp16)sW[O_W3 + k * SW1 + jj];
        A4[e] = (__fp16)sW[O_W4 + k * SW1 + jj];
        A5[e] = (__fp16)((jj < 3) ? sW[O_W5 + k * 4 + jj] : 0.f);
    }
    C1 = *reinterpret_cast<const f32x4*>(sW + O_B1 + 4 * kg);
    C2 = *reinterpret_cast<const f32x4*>(sW + O_B2 + 4 * kg);
    C3 = *reinterpret_cast<const f32x4*>(sW + O_B3 + 4 * kg);
    C4 = *reinterpret_cast<const f32x4*>(sW + O_B4 + 4 * kg);
    C5 = *reinterpret_cast<const f32x4*>(sW + O_B5 + 4 * kg);

    issueG(pa0, pa1);  // gathers + wx/wy stash for tile 1

    // ---- pipelined main loop (invariants as R14) ----
#pragma unroll 1
    for (int t = 0; t < TPB; ++t) {
        const int cur = t & 1;
        if (t + 2 < TPB) loadX(t + 2, pb0, pb1, pb2);
        runTile(t, cur);
        if (t + 1 < TPB) interpPackWrite(pa0, pa1, pa2, cur ^ 1);
        pa0 = pb0; pa1 = pb1; pa2 = pb2;
        __syncthreads();
        if (t + 2 < TPB) issueG(pa0, pa1);
    }
}

extern "C" void kernel_launch(void* const* d_in, const int* in_sizes, int n_in,
                              void* d_out, int out_size, void* d_ws, size_t ws_size,
                              hipStream_t stream) {
    const float* x  = (const float*)d_in[0];
    const float* fm = (const float*)d_in[1];
    const float* W1 = (const float*)d_in[2];
    const float* b1 = (const float*)d_in[3];
    const float* W2 = (const float*)d_in[4];
    const float* b2 = (const float*)d_in[5];
    const float* W3 = (const float*)d_in[6];
    const float* b3 = (const float*)d_in[7];
    const float* W4 = (const float*)d_in[8];
    const float* b4 = (const float*)d_in[9];
    const float* W5 = (const float*)d_in[10];
    const float* b5 = (const float*)d_in[11];
    float* out = (float*)d_out;

    const int n = in_sizes[0] / 3;  // 4,000,000 points
    const int tiles = (n + BLK - 1) / BLK;
    const int grid = (tiles + TPB - 1) / TPB;

    const size_t need = (size_t)HWSZ * sizeof(f16x4);  // 2 MB f16 table
    if (ws_size >= need) {
        f16x4* fmT = (f16x4*)d_ws;
        fm_transpose_h<<<(HWSZ + 255) / 256, 256, 0, stream>>>(fm, fmT);
        mlp_fused<true><<<grid, BLK, 0, stream>>>(x, (const void*)fmT, W1, b1,
                                                  W2, b2, W3, b3, W4, b4, W5, b5,
                                                  out, n);
    } else {
        mlp_fused<false><<<grid, BLK, 0, stream>>>(x, (const void*)fm, W1, b1,
                                                   W2, b2, W3, b3, W4, b4, W5, b5,
                                                   out, n);
    }
}